// Round 1
// baseline (2952.116 us; speedup 1.0000x reference)
//
#include <hip/hip_runtime.h>
#include <hip/hip_bf16.h>

// Problem constants: B=8, S=1024, E=1024, H=16, D=64
#define PB 8
#define PS 1024
#define PE 1024
#define PH 16
#define PD 64
#define EPSLN 1e-3f

// ---------------------------------------------------------------------------
// Kernel 1: QKV projection. Y = X @ W, X:[8192,1024], W:[1024,1024].
// blockIdx.z selects Wq/Wk/Wv. 64x64 tile, BK=16, 256 threads, 4x4/thread.
// ---------------------------------------------------------------------------
#define TBM 64
#define TBN 64
#define TBK 16

__global__ __launch_bounds__(256) void qkv_gemm(
    const float* __restrict__ X,
    const float* __restrict__ Wq,
    const float* __restrict__ Wk,
    const float* __restrict__ Wv,
    float* __restrict__ Qo,
    float* __restrict__ Ko,
    float* __restrict__ Vo)
{
    const int M = PB * PS, N = PE, K = PE;
    const float* W = (blockIdx.z == 0) ? Wq : (blockIdx.z == 1) ? Wk : Wv;
    float* O = (blockIdx.z == 0) ? Qo : (blockIdx.z == 1) ? Ko : Vo;

    __shared__ float As[TBM][TBK + 1];  // +1 pad: conflict-free column reads
    __shared__ float Bs[TBK][TBN];

    const int tx = threadIdx.x & 15;   // 0..15
    const int ty = threadIdx.x >> 4;   // 0..15
    const int row0 = blockIdx.y * TBM;
    const int col0 = blockIdx.x * TBN;

    float acc[4][4] = {};

    for (int k0 = 0; k0 < K; k0 += TBK) {
        for (int l = threadIdx.x; l < TBM * TBK; l += 256) {
            int r = l / TBK, c = l % TBK;
            As[r][c] = X[(size_t)(row0 + r) * K + k0 + c];
        }
        for (int l = threadIdx.x; l < TBK * TBN; l += 256) {
            int r = l / TBN, c = l % TBN;
            Bs[r][c] = W[(size_t)(k0 + r) * N + col0 + c];
        }
        __syncthreads();
#pragma unroll
        for (int kk = 0; kk < TBK; ++kk) {
            float a[4], b[4];
#pragma unroll
            for (int i = 0; i < 4; ++i) a[i] = As[ty * 4 + i][kk];
#pragma unroll
            for (int j = 0; j < 4; ++j) b[j] = Bs[kk][tx * 4 + j];
#pragma unroll
            for (int i = 0; i < 4; ++i)
#pragma unroll
                for (int j = 0; j < 4; ++j) acc[i][j] += a[i] * b[j];
        }
        __syncthreads();
    }
#pragma unroll
    for (int i = 0; i < 4; ++i)
#pragma unroll
        for (int j = 0; j < 4; ++j)
            O[(size_t)(row0 + ty * 4 + i) * N + col0 + tx * 4 + j] = acc[i][j];
}

// ---------------------------------------------------------------------------
// Kernel 2: fused attention, one pass over K/V.
//   out_i = (1/l_i) * sum_j exp(s_ij - m_i) v_j  +  sum_j bias[h,i,j] v_j
// Block: 256 threads = 16 queries x 16 d-slices (4 d's each). Grid (S/16,H,B).
// bias[h][i][j] = rel[(s2-s1+1023)*16 + (j&15)],
//   s1=(h<<6)|(i>>4), s2=((i&15)<<6)|(j>>4)   (exact flat-order reinterpretation)
// ---------------------------------------------------------------------------
__global__ __launch_bounds__(256) void attn_fused(
    const float* __restrict__ Qb,
    const float* __restrict__ Kb,
    const float* __restrict__ Vb,
    const float* __restrict__ rel,
    float* __restrict__ O)
{
    const int qt = blockIdx.x;   // query tile (16 queries)
    const int h  = blockIdx.y;
    const int b  = blockIdx.z;

    const int t   = threadIdx.x;
    const int qi  = t >> 4;      // local query 0..15
    const int sub = t & 15;      // d-slice: owns d = sub*4 .. sub*4+3
    const int i   = qt * 16 + qi;

    const float scale = 0.03125f;  // E^-0.5 = 1/32 (full emb, faithful)

    __shared__ float Ks[64][64];
    __shared__ float Vs[64][64];

    const float* qrow = Qb + ((size_t)b * PS + i) * PE + h * PD;
    float qreg[4];
#pragma unroll
    for (int r = 0; r < 4; ++r) qreg[r] = qrow[sub * 4 + r];

    float m = -1e30f, l = 0.f;
    float acc[4] = {0.f, 0.f, 0.f, 0.f};
    float bacc[4] = {0.f, 0.f, 0.f, 0.f};

    const float* Kbase = Kb + ((size_t)b * PS) * PE + h * PD;
    const float* Vbase = Vb + ((size_t)b * PS) * PE + h * PD;

    const int s1 = (h << 6) | (i >> 4);
    const int s2base = (i & 15) << 6;

    for (int j0 = 0; j0 < PS; j0 += 64) {
        __syncthreads();
        for (int l4 = t; l4 < 64 * 16; l4 += 256) {
            int r = l4 >> 4, c4 = l4 & 15;
            reinterpret_cast<float4*>(&Ks[r][0])[c4] =
                reinterpret_cast<const float4*>(Kbase + (size_t)(j0 + r) * PE)[c4];
            reinterpret_cast<float4*>(&Vs[r][0])[c4] =
                reinterpret_cast<const float4*>(Vbase + (size_t)(j0 + r) * PE)[c4];
        }
        __syncthreads();

        for (int jj = 0; jj < 64; ++jj) {
            const int j = j0 + jj;
            float partial = 0.f;
#pragma unroll
            for (int r = 0; r < 4; ++r) partial += qreg[r] * Ks[jj][sub * 4 + r];
            partial += __shfl_xor(partial, 1, 16);
            partial += __shfl_xor(partial, 2, 16);
            partial += __shfl_xor(partial, 4, 16);
            partial += __shfl_xor(partial, 8, 16);
            const float s = partial * scale;

            const float mn = fmaxf(m, s);
            const float corr = __expf(m - mn);
            const float p = __expf(s - mn);
            l = l * corr + p;
            m = mn;

            const int s2 = s2base | (j >> 4);
            const int h0 = j & 15;
            int ridx = s2 - s1 + (PS - 1);
            ridx = ridx < 0 ? 0 : (ridx > 2 * PS - 2 ? 2 * PS - 2 : ridx);
            const float bv = rel[ridx * PH + h0];

#pragma unroll
            for (int r = 0; r < 4; ++r) {
                const float vv = Vs[jj][sub * 4 + r];
                acc[r] = acc[r] * corr + p * vv;
                bacc[r] += bv * vv;
            }
        }
    }

    const float invl = 1.f / l;
    float* orow = O + ((size_t)b * PS + i) * PE + h * PD;
#pragma unroll
    for (int r = 0; r < 4; ++r) orow[sub * 4 + r] = acc[r] * invl + bacc[r];
}

// ---------------------------------------------------------------------------
// Kernel 3: LayerNorm over last dim (1024), in-place on d_out.
// One block (256 threads) per row; float4 per thread.
// ---------------------------------------------------------------------------
__global__ __launch_bounds__(256) void layernorm_inplace(
    float* __restrict__ O,
    const float* __restrict__ gamma,
    const float* __restrict__ beta)
{
    const int row = blockIdx.x;
    float* p = O + (size_t)row * PE;
    const int t = threadIdx.x;

    float4 x = reinterpret_cast<float4*>(p)[t];
    float s  = x.x + x.y + x.z + x.w;
    float s2 = x.x * x.x + x.y * x.y + x.z * x.z + x.w * x.w;

#pragma unroll
    for (int off = 1; off < 64; off <<= 1) {
        s  += __shfl_xor(s, off, 64);
        s2 += __shfl_xor(s2, off, 64);
    }
    __shared__ float red[2][4];
    const int wid = t >> 6;
    if ((t & 63) == 0) { red[0][wid] = s; red[1][wid] = s2; }
    __syncthreads();
    const float ts  = red[0][0] + red[0][1] + red[0][2] + red[0][3];
    const float ts2 = red[1][0] + red[1][1] + red[1][2] + red[1][3];

    const float mu  = ts * (1.f / PE);
    const float var = ts2 * (1.f / PE) - mu * mu;
    const float inv = rsqrtf(var + EPSLN);

    const float4 g  = reinterpret_cast<const float4*>(gamma)[t];
    const float4 bb = reinterpret_cast<const float4*>(beta)[t];
    float4 y;
    y.x = (x.x - mu) * inv * g.x + bb.x;
    y.y = (x.y - mu) * inv * g.y + bb.y;
    y.z = (x.z - mu) * inv * g.z + bb.z;
    y.w = (x.w - mu) * inv * g.w + bb.w;
    reinterpret_cast<float4*>(p)[t] = y;
}

// ---------------------------------------------------------------------------
extern "C" void kernel_launch(void* const* d_in, const int* in_sizes, int n_in,
                              void* d_out, int out_size, void* d_ws, size_t ws_size,
                              hipStream_t stream) {
    (void)in_sizes; (void)n_in; (void)out_size; (void)ws_size;
    const float* x     = (const float*)d_in[0];
    const float* Wq    = (const float*)d_in[1];
    const float* Wk    = (const float*)d_in[2];
    const float* Wv    = (const float*)d_in[3];
    const float* rel   = (const float*)d_in[4];
    const float* gamma = (const float*)d_in[5];
    const float* beta  = (const float*)d_in[6];
    float* out = (float*)d_out;

    float* ws = (float*)d_ws;
    const size_t BSE = (size_t)PB * PS * PE;  // 8M floats
    float* Qb = ws;
    float* Kb = ws + BSE;
    float* Vb = ws + 2 * BSE;

    dim3 g1(PE / TBN, (PB * PS) / TBM, 3);
    qkv_gemm<<<g1, 256, 0, stream>>>(x, Wq, Wk, Wv, Qb, Kb, Vb);

    dim3 g2(PS / 16, PH, PB);
    attn_fused<<<g2, 256, 0, stream>>>(Qb, Kb, Vb, rel, out);

    layernorm_inplace<<<PB * PS, 256, 0, stream>>>(out, gamma, beta);
}

// Round 2
// 215.884 us; speedup vs baseline: 13.6746x; 13.6746x over previous
//
#include <hip/hip_runtime.h>
#include <hip/hip_bf16.h>

// Problem constants: B=8, S=1024, E=1024, H=16, D=64
#define PB 8
#define PS 1024
#define PE 1024
#define PH 16
#define PD 64
#define EPSLN 1e-3f
#define SCALE 0.03125f   // E^-0.5 = 1/32 (full emb, faithful to reference)

typedef __attribute__((ext_vector_type(8))) short bf16x8;   // 8 bf16 = 4 VGPR
typedef __attribute__((ext_vector_type(4))) float f32x4;

__device__ __forceinline__ unsigned short f2bf(float f) {
    unsigned int u = __float_as_uint(f);
    u += 0x7FFFu + ((u >> 16) & 1u);   // RNE
    return (unsigned short)(u >> 16);
}

__device__ __forceinline__ void gload_lds16(const void* g, void* l) {
    __builtin_amdgcn_global_load_lds(
        (const __attribute__((address_space(1))) unsigned int*)g,
        (__attribute__((address_space(3))) unsigned int*)l,
        16, 0, 0);
}

// ---------------------------------------------------------------------------
// Convert X f32 -> bf16 (8M elems, 8 per thread)
// ---------------------------------------------------------------------------
__global__ __launch_bounds__(256) void conv_x(
    const float* __restrict__ X, unsigned short* __restrict__ Xb)
{
    const size_t i = (size_t)blockIdx.x * 256 + threadIdx.x;
    const float4* p = reinterpret_cast<const float4*>(X) + i * 2;
    float4 a = p[0], b = p[1];
    unsigned short r[8];
    r[0] = f2bf(a.x); r[1] = f2bf(a.y); r[2] = f2bf(a.z); r[3] = f2bf(a.w);
    r[4] = f2bf(b.x); r[5] = f2bf(b.y); r[6] = f2bf(b.z); r[7] = f2bf(b.w);
    *reinterpret_cast<uint4*>(Xb + i * 8) = *reinterpret_cast<const uint4*>(r);
}

// ---------------------------------------------------------------------------
// Transpose+convert W's: Wtb[proj*1024 + n][k] = W_proj[k][n] as bf16
// ---------------------------------------------------------------------------
__global__ __launch_bounds__(256) void conv_w(
    const float* __restrict__ Wq, const float* __restrict__ Wk,
    const float* __restrict__ Wv, unsigned short* __restrict__ Wtb)
{
    const int proj = blockIdx.z;
    const float* W = (proj == 0) ? Wq : (proj == 1) ? Wk : Wv;
    __shared__ float tile[32][33];
    const int n0 = blockIdx.x * 32, k0 = blockIdx.y * 32;
    const int tx = threadIdx.x & 31, ty = threadIdx.x >> 5;  // 32 x 8
#pragma unroll
    for (int i = 0; i < 4; ++i)
        tile[ty + i * 8][tx] = W[(size_t)(k0 + ty + i * 8) * PE + n0 + tx];
    __syncthreads();
#pragma unroll
    for (int i = 0; i < 4; ++i)
        Wtb[(size_t)(proj * 1024 + n0 + ty + i * 8) * 1024 + k0 + tx] =
            f2bf(tile[tx][ty + i * 8]);
}

// ---------------------------------------------------------------------------
// QKV GEMM: C[8192][3072] bf16 = Xb[8192][1024] @ Wtb^T, MFMA 16x16x32 bf16.
// 128x128 tile, BK=64, 4 waves (2x2), global_load_lds w16, XOR-swizzled LDS.
// ---------------------------------------------------------------------------
__global__ __launch_bounds__(256) void qkv_mfma(
    const unsigned short* __restrict__ Xb,
    const unsigned short* __restrict__ Wtb,
    unsigned short* __restrict__ QKV)
{
    // XCD-chunked bijective swizzle: 1536 blocks, n-fast within chunk
    const int orig = blockIdx.x;
    const int wg = (orig & 7) * 192 + (orig >> 3);
    const int nblk = wg % 24, mblk = wg / 24;
    const int m0 = mblk * 128, n0 = nblk * 128;

    __shared__ __align__(16) unsigned short As[128 * 64];
    __shared__ __align__(16) unsigned short Bs[128 * 64];

    const int t = threadIdx.x;
    const int w = t >> 6, l = t & 63;
    const int lane15 = l & 15, lhi = l >> 4;
    const int wm = w >> 1, wn = w & 1;

    f32x4 acc[4][4] = {};

    for (int k0 = 0; k0 < 1024; k0 += 64) {
        __syncthreads();
#pragma unroll
        for (int c = 0; c < 4; ++c) {
            const int ci = (w * 4 + c) * 64 + l;      // 0..1023 chunk id
            const int r = ci >> 3;
            const int srccl = (ci & 7) ^ (r & 7);     // inverse-swizzled source
            gload_lds16(Xb  + (size_t)(m0 + r) * 1024 + k0 + srccl * 8, &As[ci * 8]);
            gload_lds16(Wtb + (size_t)(n0 + r) * 1024 + k0 + srccl * 8, &Bs[ci * 8]);
        }
        __syncthreads();
#pragma unroll
        for (int kk = 0; kk < 2; ++kk) {
            bf16x8 af[4], bf[4];
#pragma unroll
            for (int mi = 0; mi < 4; ++mi) {
                const int row = wm * 64 + mi * 16 + lane15;
                af[mi] = *reinterpret_cast<const bf16x8*>(
                    &As[row * 64 + (((kk * 4 + lhi) ^ (row & 7)) << 3)]);
            }
#pragma unroll
            for (int ni = 0; ni < 4; ++ni) {
                const int row = wn * 64 + ni * 16 + lane15;
                bf[ni] = *reinterpret_cast<const bf16x8*>(
                    &Bs[row * 64 + (((kk * 4 + lhi) ^ (row & 7)) << 3)]);
            }
#pragma unroll
            for (int mi = 0; mi < 4; ++mi)
#pragma unroll
                for (int ni = 0; ni < 4; ++ni)
                    acc[mi][ni] = __builtin_amdgcn_mfma_f32_16x16x32_bf16(
                        af[mi], bf[ni], acc[mi][ni], 0, 0, 0);
        }
    }
#pragma unroll
    for (int mi = 0; mi < 4; ++mi)
#pragma unroll
        for (int ni = 0; ni < 4; ++ni)
#pragma unroll
            for (int r = 0; r < 4; ++r) {
                const int gr = m0 + wm * 64 + mi * 16 + lhi * 4 + r;
                const int gc = n0 + wn * 64 + ni * 16 + lane15;
                QKV[(size_t)gr * 3072 + gc] = f2bf(acc[mi][ni][r]);
            }
}

// ---------------------------------------------------------------------------
// Fused attention: per (b,h,64-q-rows) block, 4 waves x 16 q-rows.
//   out = accP / l + accB, l via MFMA against all-ones fragment.
//   bias[h][i][j] = rel[clip(s2-s1+1023)*16 + (j&15)],
//     s1=(h<<6)|(i>>4), s2=((i&15)<<6)|(j>>4)
// ---------------------------------------------------------------------------
__global__ __launch_bounds__(256) void attn_mfma(
    const unsigned short* __restrict__ qkv,
    const float* __restrict__ rel,
    float* __restrict__ O)
{
    __shared__ __align__(16) unsigned short Ks[64 * 64];      // [j][k-dim] swizzled
    __shared__ __align__(16) unsigned short Vt[64 * 64];      // [d][j] swizzled
    __shared__ __align__(16) unsigned short Pb[4][16 * 64];   // per-wave P tile
    __shared__ __align__(16) unsigned short Bb[4][16 * 64];   // per-wave bias tile

    const int orig = blockIdx.x;                 // 2048 blocks
    const int wg = (orig & 7) * 256 + (orig >> 3);  // XCD-chunked, bijective
    const int qt = wg & 15;
    const int h  = (wg >> 4) & 15;
    const int b  = wg >> 8;

    const int t = threadIdx.x;
    const int w = t >> 6, l = t & 63;
    const int lane15 = l & 15, lhi = l >> 4;

    // Q fragments in registers: a[t] = Q[row=l&15][k = lhi*8 + t (+32)]
    bf16x8 aQ0, aQ1;
    {
        const size_t qrow = (size_t)(b * PS + qt * 64 + w * 16 + lane15);
        const unsigned short* qp = qkv + qrow * 3072 + h * 64 + lhi * 8;
        aQ0 = *reinterpret_cast<const bf16x8*>(qp);
        aQ1 = *reinterpret_cast<const bf16x8*>(qp + 32);
    }
    const int s1c = (h << 6) | (qt * 4 + w);

    f32x4 accP[4] = {}, accB[4] = {};
    f32x4 accL = {0.f, 0.f, 0.f, 0.f};
    bf16x8 ones;
#pragma unroll
    for (int i = 0; i < 8; ++i) ones[i] = (short)0x3F80;  // bf16 1.0

    const unsigned short* Kg = qkv + (size_t)(b * PS) * 3072 + 1024 + h * 64;
    const unsigned short* Vg = qkv + (size_t)(b * PS) * 3072 + 2048 + h * 64;

    for (int j0 = 0; j0 < PS; j0 += 64) {
        __syncthreads();
        // stage K tile [64 j][64 k-dims], 16B-chunk XOR swizzle
#pragma unroll
        for (int it = 0; it < 2; ++it) {
            const int ci = t + it * 256;
            const int r = ci >> 3, cl = ci & 7;
            uint4 d = *reinterpret_cast<const uint4*>(Kg + (size_t)(j0 + r) * 3072 + cl * 8);
            *reinterpret_cast<uint4*>(&Ks[r * 64 + (((cl) ^ (r & 7)) << 3)]) = d;
        }
        // stage V transposed: Vt[d][j], swizzled
        {
            const int j = t & 63, d0 = (t >> 6) * 16;
            const unsigned short* vp = Vg + (size_t)(j0 + j) * 3072 + d0;
            uint4 va = *reinterpret_cast<const uint4*>(vp);
            uint4 vb = *reinterpret_cast<const uint4*>(vp + 8);
            unsigned short tmp[16];
            *reinterpret_cast<uint4*>(tmp) = va;
            *reinterpret_cast<uint4*>(tmp + 8) = vb;
#pragma unroll
            for (int i = 0; i < 16; ++i) {
                const int row = d0 + i;
                Vt[row * 64 + (j ^ ((row & 7) << 3))] = tmp[i];
            }
        }
        __syncthreads();

        // S = Q K^T per 16-j chunk -> exp -> P/Bias tiles (per-wave LDS)
#pragma unroll
        for (int jt = 0; jt < 4; ++jt) {
            const int krow = jt * 16 + lane15;
            bf16x8 bK0 = *reinterpret_cast<const bf16x8*>(
                &Ks[krow * 64 + (((lhi) ^ (krow & 7)) << 3)]);
            bf16x8 bK1 = *reinterpret_cast<const bf16x8*>(
                &Ks[krow * 64 + (((4 + lhi) ^ (krow & 7)) << 3)]);
            f32x4 s = {0.f, 0.f, 0.f, 0.f};
            s = __builtin_amdgcn_mfma_f32_16x16x32_bf16(aQ0, bK0, s, 0, 0, 0);
            s = __builtin_amdgcn_mfma_f32_16x16x32_bf16(aQ1, bK1, s, 0, 0, 0);
            const int jb = (j0 >> 4) + jt;
#pragma unroll
            for (int r = 0; r < 4; ++r) {
                const int iloc = lhi * 4 + r;
                const float p = __expf(s[r] * SCALE);   // fixed m=0: |s*scale| < ~1
                int ridx = ((iloc << 6) | jb) - s1c + (PS - 1);
                ridx = ridx < 0 ? 0 : (ridx > 2 * PS - 2 ? 2 * PS - 2 : ridx);
                const float bv = rel[ridx * PH + lane15];
                const int widx = iloc * 64 + ((jt * 16 + lane15) ^ ((iloc & 7) << 3));
                Pb[w][widx] = f2bf(p);
                Bb[w][widx] = f2bf(bv);
            }
        }

        // PV + bias.V + row-sums (ones-MFMA); V frags reused for both chains
#pragma unroll
        for (int kk = 0; kk < 2; ++kk) {
            const int pidx = lane15 * 64 + (((kk * 4 + lhi) ^ (lane15 & 7)) << 3);
            bf16x8 aP = *reinterpret_cast<const bf16x8*>(&Pb[w][pidx]);
            bf16x8 aB = *reinterpret_cast<const bf16x8*>(&Bb[w][pidx]);
            accL = __builtin_amdgcn_mfma_f32_16x16x32_bf16(aP, ones, accL, 0, 0, 0);
#pragma unroll
            for (int n = 0; n < 4; ++n) {
                const int vrow = n * 16 + lane15;
                bf16x8 bV = *reinterpret_cast<const bf16x8*>(
                    &Vt[vrow * 64 + (((kk * 4 + lhi) ^ (vrow & 7)) << 3)]);
                accP[n] = __builtin_amdgcn_mfma_f32_16x16x32_bf16(aP, bV, accP[n], 0, 0, 0);
                accB[n] = __builtin_amdgcn_mfma_f32_16x16x32_bf16(aB, bV, accB[n], 0, 0, 0);
            }
        }
    }

#pragma unroll
    for (int r = 0; r < 4; ++r) {
        const float invl = 1.0f / accL[r];
        const size_t orow = (size_t)(b * PS + qt * 64 + w * 16 + lhi * 4 + r);
        float* op = O + orow * PE + h * PD + lane15;
#pragma unroll
        for (int n = 0; n < 4; ++n)
            op[n * 16] = accP[n][r] * invl + accB[n][r];
    }
}

// ---------------------------------------------------------------------------
// LayerNorm over last dim (1024), in-place on d_out.
// ---------------------------------------------------------------------------
__global__ __launch_bounds__(256) void layernorm_inplace(
    float* __restrict__ O,
    const float* __restrict__ gamma,
    const float* __restrict__ beta)
{
    const int row = blockIdx.x;
    float* p = O + (size_t)row * PE;
    const int t = threadIdx.x;

    float4 x = reinterpret_cast<float4*>(p)[t];
    float s  = x.x + x.y + x.z + x.w;
    float s2 = x.x * x.x + x.y * x.y + x.z * x.z + x.w * x.w;

#pragma unroll
    for (int off = 1; off < 64; off <<= 1) {
        s  += __shfl_xor(s, off, 64);
        s2 += __shfl_xor(s2, off, 64);
    }
    __shared__ float red[2][4];
    const int wid = t >> 6;
    if ((t & 63) == 0) { red[0][wid] = s; red[1][wid] = s2; }
    __syncthreads();
    const float ts  = red[0][0] + red[0][1] + red[0][2] + red[0][3];
    const float ts2 = red[1][0] + red[1][1] + red[1][2] + red[1][3];

    const float mu  = ts * (1.f / PE);
    const float var = ts2 * (1.f / PE) - mu * mu;
    const float inv = rsqrtf(var + EPSLN);

    const float4 g  = reinterpret_cast<const float4*>(gamma)[t];
    const float4 bb = reinterpret_cast<const float4*>(beta)[t];
    float4 y;
    y.x = (x.x - mu) * inv * g.x + bb.x;
    y.y = (x.y - mu) * inv * g.y + bb.y;
    y.z = (x.z - mu) * inv * g.z + bb.z;
    y.w = (x.w - mu) * inv * g.w + bb.w;
    reinterpret_cast<float4*>(p)[t] = y;
}

// ---------------------------------------------------------------------------
extern "C" void kernel_launch(void* const* d_in, const int* in_sizes, int n_in,
                              void* d_out, int out_size, void* d_ws, size_t ws_size,
                              hipStream_t stream) {
    (void)in_sizes; (void)n_in; (void)out_size; (void)ws_size;
    const float* x     = (const float*)d_in[0];
    const float* Wq    = (const float*)d_in[1];
    const float* Wk    = (const float*)d_in[2];
    const float* Wv    = (const float*)d_in[3];
    const float* rel   = (const float*)d_in[4];
    const float* gamma = (const float*)d_in[5];
    const float* beta  = (const float*)d_in[6];
    float* out = (float*)d_out;

    char* ws = (char*)d_ws;
    unsigned short* Xb  = (unsigned short*)ws;                       // 16 MB
    unsigned short* Wtb = (unsigned short*)(ws + 16777216);          // 6 MB
    unsigned short* QKV = (unsigned short*)(ws + 23068672);          // 48 MB

    conv_x<<<4096, 256, 0, stream>>>(x, Xb);
    conv_w<<<dim3(32, 32, 3), 256, 0, stream>>>(Wq, Wk, Wv, Wtb);
    qkv_mfma<<<1536, 256, 0, stream>>>(Xb, Wtb, QKV);
    attn_mfma<<<2048, 256, 0, stream>>>(QKV, rel, out);
    layernorm_inplace<<<PB * PS, 256, 0, stream>>>(out, gamma, beta);
}